// Round 5
// baseline (1114.080 us; speedup 1.0000x reference)
//
#include <hip/hip_runtime.h>
#include <hip/hip_bf16.h>
#include <math.h>

using bf16 = __hip_bfloat16;

#define DEV static __device__ __forceinline__

constexpr int NENT = 40000;
constexpr int DIM  = 200;
constexpr int EE   = 80000;      // edges per side
constexpr int TOTE = 2 * EE;     // 160000
constexpr int BQ   = 1024;
constexpr float EPSBN = 1e-5f;
constexpr size_t XOFF = (size_t)2 * BQ * DIM;   // x-region element offset inside d_out

// MFMA geometry: N padded to 208 (13x16), K padded to 224 (7x32)
constexpr int KP   = 224;
constexpr int NP   = 208;
constexpr int LDT  = 232;        // per-wave LDS transpose-buffer stride (ushorts), 464B rows
constexpr int MT_LOOP64 = (NENT + 63) / 64;   // 625
constexpr int MT_EDGE64 = TOTE / 64;          // 2500

typedef __attribute__((ext_vector_type(8))) short s8v;   // 8 x bf16 (4 VGPRs)
typedef __attribute__((ext_vector_type(4))) float f4v;   // MFMA accumulator

struct MP { const void* p; };    // world-dtype (bf16|f32) pointer, runtime flag

DEV float b2f(unsigned int u) { union { unsigned int i; float f; } v; v.i = u << 16; return v.f; }

DEV float ld(MP m, size_t i, int bf) {
  return bf ? b2f(((const unsigned short*)m.p)[i]) : ((const float*)m.p)[i];
}
DEV void ld8(MP m, size_t i, float* o, int bf) {
  if (bf) {
    uint4 u = *(const uint4*)((const unsigned short*)m.p + i);
    o[0]=b2f(u.x & 0xffffu); o[1]=b2f(u.x >> 16);
    o[2]=b2f(u.y & 0xffffu); o[3]=b2f(u.y >> 16);
    o[4]=b2f(u.z & 0xffffu); o[5]=b2f(u.z >> 16);
    o[6]=b2f(u.w & 0xffffu); o[7]=b2f(u.w >> 16);
  } else {
    const float4* q = (const float4*)((const float*)m.p + i);
    float4 a = q[0], b = q[1];
    o[0]=a.x; o[1]=a.y; o[2]=a.z; o[3]=a.w; o[4]=b.x; o[5]=b.y; o[6]=b.z; o[7]=b.w;
  }
}
DEV void f32load8(const float* p, float* o) {
  const float4* q = (const float4*)p;
  float4 a = q[0], b = q[1];
  o[0]=a.x; o[1]=a.y; o[2]=a.z; o[3]=a.w; o[4]=b.x; o[5]=b.y; o[6]=b.z; o[7]=b.w;
}
DEV void st(void* p, size_t i, float v, int bf) {
  if (bf) ((bf16*)p)[i] = __float2bfloat16(v);
  else    ((float*)p)[i] = v;
}
DEV unsigned short f2b(float f) {   // RNE f32 -> bf16 bits (inputs never NaN)
  union { float f; unsigned int i; } v; v.f = f;
  return (unsigned short)((v.i + 0x7fffu + ((v.i >> 16) & 1u)) >> 16);
}
DEV s8v pack8v(const float* o) {
  union { s8v v; unsigned short u[8]; } t;
#pragma unroll
  for (int j = 0; j < 8; ++j) t.u[j] = f2b(o[j]);
  return t.v;
}
DEV void unpack8(s8v v, float* o) {
  union { s8v v; unsigned short u[8]; } t; t.v = v;
#pragma unroll
  for (int j = 0; j < 8; ++j) o[j] = b2f(t.u[j]);
}

// ---------------- dtype detect ----------------
__global__ void detect_kernel(const unsigned short* __restrict__ e, int* __restrict__ flag) {
  int tid = threadIdx.x;
  int absurd = 0;
  for (int i = tid; i < 2048; i += 64) {
    int ex = (e[i] >> 7) & 0xFF;
    if (ex >= 0xD0 || (ex != 0 && ex <= 0x50)) absurd++;
  }
  for (int o = 32; o; o >>= 1) absurd += __shfl_down(absurd, o);
  if (tid == 0) *flag = (absurd > 64) ? 0 : 1;   // 1 => bf16 world
}

// ---------------- small kernels ----------------
__global__ void deg_hist_kernel(const int* __restrict__ ei,
                                float* __restrict__ deg_in, float* __restrict__ deg_out) {
  int i = blockIdx.x * 256 + threadIdx.x;
  if (i >= TOTE) return;
  atomicAdd((i < EE ? deg_in : deg_out) + ei[i], 1.0f);
}

__global__ void norm_kernel(const int* __restrict__ ei,
                            const float* __restrict__ deg_in, const float* __restrict__ deg_out,
                            float* __restrict__ normA) {
  int i = blockIdx.x * 256 + threadIdx.x;
  if (i >= TOTE) return;
  int s = ei[i], d = ei[TOTE + i];
  const float* deg = (i < EE) ? deg_in : deg_out;
  float a = deg[s], b = deg[d];
  float na = a > 0.f ? rsqrtf(a) : 0.f;
  float nb = b > 0.f ? rsqrtf(b) : 0.f;
  normA[i] = na * nb;
}

__global__ void copy_f32_kernel(MP s, float* __restrict__ d, int n, const int* __restrict__ flagp) {
  int bf = *flagp;
  int i = blockIdx.x * 256 + threadIdx.x;
  if (i < n) d[i] = ld(s, i, bf);
}

__global__ void mat200_kernel(MP A, int a_use_flag, MP B, float* __restrict__ C,
                              const int* __restrict__ flagp) {
  int bf = *flagp;
  int abf = a_use_flag ? bf : 0;
  int i = blockIdx.x, c = threadIdx.x;
  if (c >= DIM) return;
  float acc = 0.f;
  for (int d = 0; d < DIM; ++d)
    acc = fmaf(ld(A, (size_t)i * DIM + d, abf), ld(B, (size_t)d * DIM + c, bf), acc);
  C[(size_t)i * DIM + c] = acc;
}

// Bt[n][k] = W^T padded to [208][224] bf16, optionally folding loop_rel
__global__ void btprep_kernel(MP w, MP lrp, int has_lr, unsigned short* __restrict__ bt,
                              const int* __restrict__ flagp) {
  int bf = *flagp;
  int n = blockIdx.x, k = threadIdx.x;
  if (k >= KP) return;
  float v = 0.f;
  if (n < DIM && k < DIM) {
    v = ld(w, (size_t)k * DIM + n, bf);
    if (has_lr) v *= ld(lrp, k, bf);
  }
  bt[(size_t)n * KP + k] = f2b(v);
}

// ---------------- loop (self-edge) MFMA: agg = x @ wp'  (M=64, direct A-frag loads, no LDS) ----
__global__ __launch_bounds__(256, 4) void loop_mfma(
    MP x, size_t xoff, const unsigned short* __restrict__ Bt,
    float* __restrict__ agg, const int* __restrict__ flagp) {
  const int bf   = *flagp;
  const int tid  = threadIdx.x;
  const int lane = tid & 63;
  const int w    = tid >> 6;
  const int m    = lane & 15;
  const int quad = lane >> 4;
  const int m0   = blockIdx.x * 64;
  const int row  = m0 + w * 16 + m;

  s8v afr[7];
#pragma unroll
  for (int kc = 0; kc < 7; ++kc) {
    const int k0 = kc * 32 + quad * 8;
    float o[8] = {0,0,0,0,0,0,0,0};
    if (row < NENT && k0 < DIM) ld8(x, xoff + (size_t)row * DIM + k0, o, bf);
    afr[kc] = pack8v(o);
  }

  f4v acc[13];
#pragma unroll
  for (int t = 0; t < 13; ++t) acc[t] = (f4v){0.f, 0.f, 0.f, 0.f};

  const unsigned short* btl = Bt + (size_t)m * KP + quad * 8;
#pragma unroll
  for (int kc = 0; kc < 7; ++kc) {
    const int k0 = kc * 32;
#pragma unroll
    for (int nt = 0; nt < 13; ++nt) {
      s8v b = __builtin_bit_cast(s8v, *(const uint4*)(btl + (size_t)nt * 16 * KP + k0));
      acc[nt] = __builtin_amdgcn_mfma_f32_16x16x32_bf16(afr[kc], b, acc[nt], 0, 0, 0);
    }
  }

#pragma unroll
  for (int i = 0; i < 4; ++i) {
    const int grow = m0 + w * 16 + quad * 4 + i;
    if (grow < NENT) {
      float* ap = agg + (size_t)grow * DIM;
#pragma unroll
      for (int nt = 0; nt < 13; ++nt) {
        int n = nt * 16 + m;
        if (n < DIM) ap[n] = acc[nt][i];
      }
    }
  }
}

// ---------------- fused edge kernel v2: barrier-free, register A-frag gathers ----------------
// Wave w owns edges [m0+16w, m0+16w+16). All gathers go straight into MFMA A-frag registers.
// Only LDS use: per-wave 16x232 bf16 transpose buffer for the qual C->A layout change.
__global__ __launch_bounds__(256, 4) void edge_fused(
    MP x, size_t xoff, const float* __restrict__ re,
    const int* __restrict__ ei, const int* __restrict__ ety,
    const int* __restrict__ qe, const int* __restrict__ qr,
    const float* __restrict__ normA,
    const unsigned short* __restrict__ BtQ,
    const unsigned short* __restrict__ BtIn, const unsigned short* __restrict__ BtOut,
    float* __restrict__ agg, const int* __restrict__ flagp) {
  __shared__ unsigned short T[4][16][LDT];   // 29.7 KB, wave-private slices

  const int bf   = *flagp;
  const int tid  = threadIdx.x;
  const int lane = tid & 63;
  const int w    = tid >> 6;
  const int m    = lane & 15;
  const int quad = lane >> 4;
  const int m0   = blockIdx.x * 64;
  const int side = (m0 >= EE) ? 1 : 0;
  const int e    = m0 + w * 16 + m;          // this lane's edge (A-frag row)

  const int iq0 = qe[e], iq1 = qe[TOTE + e];
  const int ir0 = qr[e], ir1 = qr[TOTE + e];
  const int isrc = ei[e];

  // t1 = x[qe0]*re[qr0] + x[qe1]*re[qr1], gathered directly in A-frag layout
  s8v t1f[7];
#pragma unroll
  for (int kc = 0; kc < 7; ++kc) {
    const int k0 = kc * 32 + quad * 8;
    float o[8] = {0,0,0,0,0,0,0,0};
    if (k0 < DIM) {   // k0 <= 192, reads [k0, k0+8) fully in-bounds
      float xa[8], ra[8], xb[8], rb[8];
      ld8(x, xoff + (size_t)iq0 * DIM + k0, xa, bf);
      f32load8(re + (size_t)ir0 * DIM + k0, ra);
      ld8(x, xoff + (size_t)iq1 * DIM + k0, xb, bf);
      f32load8(re + (size_t)ir1 * DIM + k0, rb);
#pragma unroll
      for (int j = 0; j < 8; ++j) o[j] = xa[j] * ra[j] + xb[j] * rb[j];
    }
    t1f[kc] = pack8v(o);
  }

  f4v acc[13];
#pragma unroll
  for (int t = 0; t < 13; ++t) acc[t] = (f4v){0.f, 0.f, 0.f, 0.f};

  // GEMM 1: qual = t1 @ w_q^T
  {
    const unsigned short* btl = BtQ + (size_t)m * KP + quad * 8;
#pragma unroll
    for (int kc = 0; kc < 7; ++kc) {
      const int k0 = kc * 32;
#pragma unroll
      for (int nt = 0; nt < 13; ++nt) {
        s8v b = __builtin_bit_cast(s8v, *(const uint4*)(btl + (size_t)nt * 16 * KP + k0));
        acc[nt] = __builtin_amdgcn_mfma_f32_16x16x32_bf16(t1f[kc], b, acc[nt], 0, 0, 0);
      }
    }
  }

  // x[src] A-frags — issued now so their latency overlaps epilogue-1 work
  s8v xsf[7];
#pragma unroll
  for (int kc = 0; kc < 7; ++kc) {
    const int k0 = kc * 32 + quad * 8;
    float o[8] = {0,0,0,0,0,0,0,0};
    if (k0 < DIM) ld8(x, xoff + (size_t)isrc * DIM + k0, o, bf);
    xsf[kc] = pack8v(o);
  }

  // epilogue 1: rel_e = 0.5*(re[ety] + qual) -> wave-private LDS (C-layout write)
#pragma unroll
  for (int i = 0; i < 4; ++i) {
    const int lr = quad * 4 + i;               // row within tile
    const int ge = m0 + w * 16 + lr;           // global edge
    const float* rerow = re + (size_t)ety[ge] * DIM;
#pragma unroll
    for (int nt = 0; nt < 13; ++nt) {
      int n = nt * 16 + m;
      float v = 0.f;
      if (n < DIM) v = 0.5f * (rerow[n] + acc[nt][i]);
      T[w][lr][n] = f2b(v);
    }
    T[w][lr][NP + m] = 0;                      // zero k-pad 208..224
  }
  __asm__ __volatile__("s_waitcnt lgkmcnt(0)" ::: "memory");  // order LDS writes -> reads (within wave)

#pragma unroll
  for (int t = 0; t < 13; ++t) acc[t] = (f4v){0.f, 0.f, 0.f, 0.f};

  // GEMM 2: msg = (x[src] .* rel_e) @ (w_in|w_out)^T ; A built per k-chunk from LDS (A-layout) x regs
  {
    const unsigned short* btl = (side ? BtOut : BtIn) + (size_t)m * KP + quad * 8;
#pragma unroll
    for (int kc = 0; kc < 7; ++kc) {
      const int k0 = kc * 32;
      s8v relv = *(const s8v*)&T[w][m][k0 + quad * 8];
      float rf[8], xf[8], of[8];
      unpack8(relv, rf);
      unpack8(xsf[kc], xf);
#pragma unroll
      for (int j = 0; j < 8; ++j) of[j] = rf[j] * xf[j];
      s8v a = pack8v(of);
#pragma unroll
      for (int nt = 0; nt < 13; ++nt) {
        s8v b = __builtin_bit_cast(s8v, *(const uint4*)(btl + (size_t)nt * 16 * KP + k0));
        acc[nt] = __builtin_amdgcn_mfma_f32_16x16x32_bf16(a, b, acc[nt], 0, 0, 0);
      }
    }
  }

  // epilogue 2: agg[dst] += msg * norm
#pragma unroll
  for (int i = 0; i < 4; ++i) {
    const int lr = quad * 4 + i;
    const int ge = m0 + w * 16 + lr;
    const float nv = normA[ge];
    float* ap = agg + (size_t)ei[TOTE + ge] * DIM;
#pragma unroll
    for (int nt = 0; nt < 13; ++nt) {
      int n = nt * 16 + m;
      if (n < DIM) atomicAdd(ap + n, acc[nt][i] * nv);
    }
  }
}

// ---------------- BatchNorm + gather ----------------
__global__ __launch_bounds__(256) void bn_reduce_kernel(const float* __restrict__ agg,
                                                        float* __restrict__ sums) {
  int tid = threadIdx.x;
  if (tid >= DIM) return;
  int row0 = blockIdx.x * 160;
  float s = 0.f, s2 = 0.f;
  for (int r = row0; r < row0 + 160; ++r) {
    float v = agg[(size_t)r * DIM + tid] * (1.f / 3.f);
    s += v; s2 += v * v;
  }
  atomicAdd(&sums[tid], s);
  atomicAdd(&sums[DIM + tid], s2);
}

__global__ __launch_bounds__(256) void bn_apply_kernel(const float* __restrict__ agg,
                                                       const float* __restrict__ sums,
                                                       MP gamma, MP beta,
                                                       void* __restrict__ xout, size_t ooff,
                                                       const int* __restrict__ flagp) {
  __shared__ float sc[DIM], sh[DIM];
  const int bf = *flagp;
  int tid = threadIdx.x;
  if (tid < DIM) {
    float mean = sums[tid] * (1.f / NENT);
    float var  = sums[DIM + tid] * (1.f / NENT) - mean * mean;
    float s = ld(gamma, tid, bf) * rsqrtf(var + EPSBN);
    sc[tid] = s;
    sh[tid] = ld(beta, tid, bf) - mean * s;
  }
  __syncthreads();
  int stride = gridDim.x * blockDim.x;
  for (int i = blockIdx.x * blockDim.x + tid; i < NENT * DIM; i += stride) {
    int c = i % DIM;
    float v = agg[i] * (1.f / 3.f);
    st(xout, ooff + i, tanhf(fmaf(v, sc[c], sh[c])), bf);
  }
}

__global__ void gather_kernel(void* __restrict__ out, const float* __restrict__ rfin,
                              const int* __restrict__ sub, const int* __restrict__ rel,
                              const int* __restrict__ flagp) {
  const int bf = *flagp;
  int i = blockIdx.x * 256 + threadIdx.x;
  MP xm; xm.p = out;
  if (i < BQ * DIM) {
    int b = i / DIM, c = i - b * DIM;
    st(out, i, ld(xm, XOFF + (size_t)sub[b] * DIM + c, bf), bf);
  } else if (i < 2 * BQ * DIM) {
    int j = i - BQ * DIM;
    int b = j / DIM, c = j - b * DIM;
    st(out, i, rfin[(size_t)rel[b] * DIM + c], bf);
  }
}

// ---------------- launch ----------------
extern "C" void kernel_launch(void* const* d_in, const int* in_sizes, int n_in,
                              void* d_out, int out_size, void* d_ws, size_t ws_size,
                              hipStream_t stream) {
  (void)in_sizes; (void)n_in; (void)out_size; (void)ws_size;
  const int* ei  = (const int*)d_in[0];
  const int* ety = (const int*)d_in[1];
  const int* qe  = (const int*)d_in[2];
  const int* qr  = (const int*)d_in[3];
  const int* sub = (const int*)d_in[4];
  const int* rel = (const int*)d_in[5];
  MP x0 = { d_in[6] };
  MP ir = { d_in[7] };
  MP w_loop[2] = { { d_in[8] },  { d_in[17] } };
  MP w_in[2]   = { { d_in[9] },  { d_in[18] } };
  MP w_out[2]  = { { d_in[10] }, { d_in[19] } };
  MP w_rel[2]  = { { d_in[11] }, { d_in[20] } };
  MP w_q[2]    = { { d_in[12] }, { d_in[21] } };
  MP lr[2]     = { { d_in[13] }, { d_in[22] } };
  MP gamma[2]  = { { d_in[15] }, { d_in[24] } };
  MP beta[2]   = { { d_in[16] }, { d_in[25] } };

  float* ws = (float*)d_ws;
  float* deg_in   = ws;                         // 40000
  float* deg_out  = ws + 40000;                 // 40000
  float* sums1    = ws + 80000;                 // 400
  float* sums2    = ws + 80400;                 // 400
  int*   flag     = (int*)(ws + 80800);         // 16
  float* normA    = ws + 80816;                 // 160000
  float* rel1     = ws + 240816;                // [200,200] f32
  float* rel2     = ws + 280816;
  float* rfin     = ws + 320816;
  unsigned short* bt = (unsigned short*)(ws + 440816);  // 8 x [208][224] bf16
  float* agg      = ws + 18547184;              // [40000][200] f32 (offset proven safe in r3)

  hipMemsetAsync(ws, 0, 80800 * sizeof(float), stream);  // deg + sums

  detect_kernel<<<1, 64, 0, stream>>>((const unsigned short*)d_in[6], flag);
  deg_hist_kernel<<<(TOTE + 255) / 256, 256, 0, stream>>>(ei, deg_in, deg_out);
  norm_kernel<<<(TOTE + 255) / 256, 256, 0, stream>>>(ei, deg_in, deg_out, normA);
  copy_f32_kernel<<<(DIM * DIM + 255) / 256, 256, 0, stream>>>(ir, rel1, DIM * DIM, flag);
  mat200_kernel<<<DIM, 256, 0, stream>>>(ir, 1, w_rel[0], rel2, flag);
  MP rel2m = { rel2 };
  mat200_kernel<<<DIM, 256, 0, stream>>>(rel2m, 0, w_rel[1], rfin, flag);

  // Bt: [0]=wq1 [1]=win1 [2]=wout1 [3]=wp1 [4]=wq2 [5]=win2 [6]=wout2 [7]=wp2
  MP nullmp = { nullptr };
  btprep_kernel<<<NP, 256, 0, stream>>>(w_q[0],   nullmp, 0, bt + 0ull * NP * KP, flag);
  btprep_kernel<<<NP, 256, 0, stream>>>(w_in[0],  nullmp, 0, bt + 1ull * NP * KP, flag);
  btprep_kernel<<<NP, 256, 0, stream>>>(w_out[0], nullmp, 0, bt + 2ull * NP * KP, flag);
  btprep_kernel<<<NP, 256, 0, stream>>>(w_loop[0], lr[0], 1, bt + 3ull * NP * KP, flag);
  btprep_kernel<<<NP, 256, 0, stream>>>(w_q[1],   nullmp, 0, bt + 4ull * NP * KP, flag);
  btprep_kernel<<<NP, 256, 0, stream>>>(w_in[1],  nullmp, 0, bt + 5ull * NP * KP, flag);
  btprep_kernel<<<NP, 256, 0, stream>>>(w_out[1], nullmp, 0, bt + 6ull * NP * KP, flag);
  btprep_kernel<<<NP, 256, 0, stream>>>(w_loop[1], lr[1], 1, bt + 7ull * NP * KP, flag);

  MP x1 = { d_out };

  // ---- layer 1 ----
  loop_mfma<<<MT_LOOP64, 256, 0, stream>>>(x0, 0, bt + 3ull * NP * KP, agg, flag);
  edge_fused<<<MT_EDGE64, 256, 0, stream>>>(x0, 0, rel1, ei, ety, qe, qr, normA,
                                            bt + 0ull * NP * KP, bt + 1ull * NP * KP,
                                            bt + 2ull * NP * KP, agg, flag);
  bn_reduce_kernel<<<NENT / 160, 256, 0, stream>>>(agg, sums1);
  bn_apply_kernel<<<2048, 256, 0, stream>>>(agg, sums1, gamma[0], beta[0], d_out, XOFF, flag);

  // ---- layer 2 (x1 lives in d_out x-region) ----
  loop_mfma<<<MT_LOOP64, 256, 0, stream>>>(x1, XOFF, bt + 7ull * NP * KP, agg, flag);
  edge_fused<<<MT_EDGE64, 256, 0, stream>>>(x1, XOFF, rel2, ei, ety, qe, qr, normA,
                                            bt + 4ull * NP * KP, bt + 5ull * NP * KP,
                                            bt + 6ull * NP * KP, agg, flag);
  bn_reduce_kernel<<<NENT / 160, 256, 0, stream>>>(agg, sums2);
  bn_apply_kernel<<<2048, 256, 0, stream>>>(agg, sums2, gamma[1], beta[1], d_out, XOFF, flag);

  gather_kernel<<<(2 * BQ * DIM + 255) / 256, 256, 0, stream>>>(d_out, rfin, sub, rel, flag);
}